// Round 5
// baseline (105.209 us; speedup 1.0000x reference)
//
#include <hip/hip_runtime.h>

// Problem constants
#define NB 16
#define NC 256
#define NL 1024
#define NQ 64
#define NU 64
#define N2C 512
#define NINTER 4096
#define CB 4  // gamma channels per fused block (beta partners ride along)

// ---------------------------------------------------------------------------
// Kernel A: A[b, c2, q] = sum_u u_i[b,u] * W[c2, u*64 + q]
// grid = 512 (c2), block = 256 (4 waves; u split across waves).
// W read exactly once, coalesced. ~2-3 us, latency-bound.
// ---------------------------------------------------------------------------
__global__ __launch_bounds__(256) void calc_A_kernel(
    const float* __restrict__ u_i, const float* __restrict__ W,
    float* __restrict__ A) {
  __shared__ float su[NB * NU];      // 4 KB
  __shared__ float part[4][NB][NQ];  // 16 KB
  const int t = threadIdx.x;
  const int c2 = blockIdx.x;
  const int q = t & 63;
  const int u4 = t >> 6;  // wave id 0..3

#pragma unroll
  for (int k = 0; k < 4; ++k) su[t + k * 256] = u_i[t + k * 256];
  __syncthreads();

  float acc[NB];
#pragma unroll
  for (int b = 0; b < NB; ++b) acc[b] = 0.0f;

  const float* Wrow = W + c2 * NINTER + u4 * 16 * NQ;
#pragma unroll
  for (int uu = 0; uu < 16; ++uu) {
    const float w = Wrow[uu * NQ + q];  // coalesced 256B/wave
    const int u = u4 * 16 + uu;         // wave-uniform
#pragma unroll
    for (int b = 0; b < NB; ++b) acc[b] = fmaf(su[b * NU + u], w, acc[b]);
  }
#pragma unroll
  for (int b = 0; b < NB; ++b) part[u4][b][q] = acc[b];
  __syncthreads();

#pragma unroll
  for (int i = 0; i < 4; ++i) {
    const int b = (t >> 6) * 4 + i;
    const float s =
        part[0][b][q] + part[1][b][q] + part[2][b][q] + part[3][b][q];
    A[(b * N2C + c2) * NQ + q] = s;
  }
}

// ---------------------------------------------------------------------------
// Fused v5: stats + style-GEMM + apply.
// grid = 16b * 64cb = 1024 blocks (4 blocks/CU -> 4 waves/SIMD, 2x v4's
// occupancy), block = 256 (4 waves). Block handles 4 gamma channels + 4 beta
// partners over full L=1024. Thread t owns float4 L-column t for all 8 rows
// (zero e-read redundancy within a block). x read once (staged via LDS).
// LDS: xs 16KB + As 2KB -> ~18.3KB.
// Stats: one wave per channel row (4 rows, 4 waves), full-wave shfl reduce.
// ---------------------------------------------------------------------------
__device__ __forceinline__ void fma4(float4& acc, float a, const float4& e) {
  acc.x = fmaf(a, e.x, acc.x);
  acc.y = fmaf(a, e.y, acc.y);
  acc.z = fmaf(a, e.z, acc.z);
  acc.w = fmaf(a, e.w, acc.w);
}

__global__ __launch_bounds__(256) void fused_kernel(
    const float* __restrict__ x, const float* __restrict__ e,
    const float* __restrict__ tt, const float* __restrict__ V,
    const float* __restrict__ bias, const float* __restrict__ A,
    float* __restrict__ out) {
  __shared__ float xs[CB][NL];      // 16 KB
  __shared__ float As[2 * CB][NQ];  // 2 KB
  __shared__ float sm[CB], sr[CB];

  const int blk = blockIdx.x;
  const int b = blk >> 6;          // 0..15
  const int c0 = (blk & 63) * CB;  // 0..252
  const int t = threadIdx.x;

  // ---- Early loads: first e-rows + tt (latency hides under phases 1-2) ----
  const float4* ef = reinterpret_cast<const float4*>(e + b * NQ * NL) + t;
  float4 n0 = ef[0 * 256];
  float4 n1 = ef[1 * 256];
  float4 n2 = ef[2 * 256];
  float4 n3 = ef[3 * 256];
  const float4 tv = reinterpret_cast<const float4*>(tt + b * NL)[t];

  // ---- Phase 1: stage A (8 rows x 64 q) into LDS (threads 0..127) ----
  if (t < 2 * CB * 16) {
    const int fr = t >> 4;  // 0..7 row
    const int fc = t & 15;  // float4 col
    const int ar = (fr < CB) ? (c0 + fr) : (NC + c0 + fr - CB);
    *reinterpret_cast<float4*>(&As[fr][fc * 4]) =
        reinterpret_cast<const float4*>(A + (b * N2C + ar) * NQ)[fc];
  }

  // ---- Phase 2: x -> LDS + stats (one wave per channel row) ----
  {
    const int rw = t >> 6;  // wave id = row 0..3
    const int cl = t & 63;
    const float* xrow = x + (b * NC + c0 + rw) * NL;
    float s = 0.0f, ss = 0.0f;
#pragma unroll
    for (int k = 0; k < 4; ++k) {
      const float4 v = reinterpret_cast<const float4*>(xrow)[cl + 64 * k];
      *reinterpret_cast<float4*>(&xs[rw][(cl + 64 * k) * 4]) = v;
      s += (v.x + v.y) + (v.z + v.w);
      ss = fmaf(v.x, v.x, fmaf(v.y, v.y, fmaf(v.z, v.z, fmaf(v.w, v.w, ss))));
    }
#pragma unroll
    for (int off = 32; off >= 1; off >>= 1) {
      s += __shfl_xor(s, off, 64);
      ss += __shfl_xor(ss, off, 64);
    }
    if (cl == 0) {
      const float m = s * (1.0f / NL);
      sm[rw] = m;
      sr[rw] = rsqrtf(ss * (1.0f / NL) - m * m + 1e-5f);
    }
  }
  __syncthreads();

  // ---- Phase 3: style GEMM, register-double-buffered e ----
  float4 acc[2 * CB];
#pragma unroll
  for (int r = 0; r < 2 * CB; ++r) acc[r] = make_float4(0.f, 0.f, 0.f, 0.f);

#pragma unroll 1
  for (int q0 = 0; q0 < NQ; q0 += 4) {
    const float4 e0 = n0, e1 = n1, e2 = n2, e3 = n3;
    if (q0 + 4 < NQ) {
      const float4* nf = ef + (q0 + 4) * 256;
      n0 = nf[0 * 256];
      n1 = nf[1 * 256];
      n2 = nf[2 * 256];
      n3 = nf[3 * 256];
    }
#pragma unroll
    for (int r = 0; r < 2 * CB; ++r) {
      const float4 a = *reinterpret_cast<const float4*>(&As[r][q0]);
      fma4(acc[r], a.x, e0);
      fma4(acc[r], a.y, e1);
      fma4(acc[r], a.z, e2);
      fma4(acc[r], a.w, e3);
    }
  }

  // ---- Phase 4: apply ----
#pragma unroll
  for (int r = 0; r < CB; ++r) {
    const int c = c0 + r;
    const float vg = V[c], vb = V[c + NC];
    const float bg = bias[c], bb = bias[c + NC];
    const float m = sm[r], rs = sr[r];
    const float4 xv = *reinterpret_cast<const float4*>(&xs[r][t * 4]);
    const float4 g = acc[r];
    const float4 p = acc[r + CB];
    float4 o;
    o.x = fmaf(1.0f + g.x + fmaf(tv.x, vg, bg), (xv.x - m) * rs,
               p.x + fmaf(tv.x, vb, bb));
    o.y = fmaf(1.0f + g.y + fmaf(tv.y, vg, bg), (xv.y - m) * rs,
               p.y + fmaf(tv.y, vb, bb));
    o.z = fmaf(1.0f + g.z + fmaf(tv.z, vg, bg), (xv.z - m) * rs,
               p.z + fmaf(tv.z, vb, bb));
    o.w = fmaf(1.0f + g.w + fmaf(tv.w, vg, bg), (xv.w - m) * rs,
               p.w + fmaf(tv.w, vb, bb));
    reinterpret_cast<float4*>(out + (b * NC + c) * NL)[t] = o;
  }
}

// ---------------------------------------------------------------------------
extern "C" void kernel_launch(void* const* d_in, const int* in_sizes, int n_in,
                              void* d_out, int out_size, void* d_ws,
                              size_t ws_size, hipStream_t stream) {
  const float* x = (const float*)d_in[0];     // (16,256,1024)
  const float* u_i = (const float*)d_in[1];   // (16,64)
  const float* e = (const float*)d_in[2];     // (16,64,1024)
  const float* tt = (const float*)d_in[3];    // (16,1,1024)
  const float* W = (const float*)d_in[4];     // (512,4096)
  const float* V = (const float*)d_in[5];     // (512,1)
  const float* bias = (const float*)d_in[6];  // (512,)
  float* out = (float*)d_out;                 // (16,256,1024)

  float* A = (float*)d_ws;  // 16*512*64 floats = 2 MB

  calc_A_kernel<<<N2C, 256, 0, stream>>>(u_i, W, A);
  fused_kernel<<<NB * 64, 256, 0, stream>>>(x, e, tt, V, bias, A, out);
}

// Round 6
// 101.534 us; speedup vs baseline: 1.0362x; 1.0362x over previous
//
#include <hip/hip_runtime.h>

// Problem constants
#define NB 16
#define NC 256
#define NL 1024
#define NQ 64
#define NU 64
#define N2C 512
#define NINTER 4096
#define CB 8  // gamma channels per fused block (beta partners ride along)

// ---------------------------------------------------------------------------
// Kernel A: A[b, c2, q] = sum_u u_i[b,u] * W[c2, u*64 + q]
// grid = 512 (c2), block = 256 (4 waves; u split across waves).
// W read exactly once, coalesced. ~2-3 us, latency-bound.
// ---------------------------------------------------------------------------
__global__ __launch_bounds__(256) void calc_A_kernel(
    const float* __restrict__ u_i, const float* __restrict__ W,
    float* __restrict__ A) {
  __shared__ float su[NB * NU];      // 4 KB
  __shared__ float part[4][NB][NQ];  // 16 KB
  const int t = threadIdx.x;
  const int c2 = blockIdx.x;
  const int q = t & 63;
  const int u4 = t >> 6;  // wave id 0..3

#pragma unroll
  for (int k = 0; k < 4; ++k) su[t + k * 256] = u_i[t + k * 256];
  __syncthreads();

  float acc[NB];
#pragma unroll
  for (int b = 0; b < NB; ++b) acc[b] = 0.0f;

  const float* Wrow = W + c2 * NINTER + u4 * 16 * NQ;
#pragma unroll
  for (int uu = 0; uu < 16; ++uu) {
    const float w = Wrow[uu * NQ + q];  // coalesced 256B/wave
    const int u = u4 * 16 + uu;         // wave-uniform
#pragma unroll
    for (int b = 0; b < NB; ++b) acc[b] = fmaf(su[b * NU + u], w, acc[b]);
  }
#pragma unroll
  for (int b = 0; b < NB; ++b) part[u4][b][q] = acc[b];
  __syncthreads();

#pragma unroll
  for (int i = 0; i < 4; ++i) {
    const int b = (t >> 6) * 4 + i;
    const float s =
        part[0][b][q] + part[1][b][q] + part[2][b][q] + part[3][b][q];
    A[(b * N2C + c2) * NQ + q] = s;
  }
}

// ---------------------------------------------------------------------------
// Fused (best-measured config, = round-4 v4): stats + style-GEMM + apply.
// grid = 16b * 32cb = 512 blocks (2 blocks/CU), block = 256 (4 waves).
// Block handles 8 gamma channels + 8 beta partners over full L=1024.
// Thread t owns float4 L-column t for all 16 c2-rows -> zero e-read
// redundancy. x read ONCE (staged to LDS, reused by apply). e-loads
// register double-buffered; first prefetch + tt load issued before the
// x/stats phase so HBM latency hides under it.
// LDS: xs 32KB + As 4KB -> 36.3KB.
// ---------------------------------------------------------------------------
__device__ __forceinline__ void fma4(float4& acc, float a, const float4& e) {
  acc.x = fmaf(a, e.x, acc.x);
  acc.y = fmaf(a, e.y, acc.y);
  acc.z = fmaf(a, e.z, acc.z);
  acc.w = fmaf(a, e.w, acc.w);
}

__global__ __launch_bounds__(256) void fused_kernel(
    const float* __restrict__ x, const float* __restrict__ e,
    const float* __restrict__ tt, const float* __restrict__ V,
    const float* __restrict__ bias, const float* __restrict__ A,
    float* __restrict__ out) {
  __shared__ float xs[CB][NL];      // 32 KB
  __shared__ float As[2 * CB][NQ];  // 4 KB
  __shared__ float sm[CB], sr[CB];

  const int blk = blockIdx.x;
  const int b = blk >> 5;
  const int c0 = (blk & 31) * CB;
  const int t = threadIdx.x;

  // ---- Early loads: first e-rows + tt (latency hides under phases 1-2) ----
  const float4* ef = reinterpret_cast<const float4*>(e + b * NQ * NL) + t;
  float4 n0 = ef[0 * 256];
  float4 n1 = ef[1 * 256];
  float4 n2 = ef[2 * 256];
  float4 n3 = ef[3 * 256];
  const float4 tv = reinterpret_cast<const float4*>(tt + b * NL)[t];

  // ---- Phase 1: stage A (16 rows x 64 q) into LDS ----
  {
    const int fr = t >> 4;  // 0..15 row
    const int fc = t & 15;  // float4 col
    const int ar = (fr < CB) ? (c0 + fr) : (NC + c0 + fr - CB);
    *reinterpret_cast<float4*>(&As[fr][fc * 4]) =
        reinterpret_cast<const float4*>(A + (b * N2C + ar) * NQ)[fc];
  }

  // ---- Phase 2: x -> LDS + stats (row per 32-lane group) ----
  {
    const int rw = t >> 5;  // 0..7
    const int cl = t & 31;
    const float* xrow = x + (b * NC + c0 + rw) * NL;
    float s = 0.0f, ss = 0.0f;
#pragma unroll
    for (int k = 0; k < 8; ++k) {
      const float4 v = reinterpret_cast<const float4*>(xrow)[cl + 32 * k];
      *reinterpret_cast<float4*>(&xs[rw][(cl + 32 * k) * 4]) = v;
      s += (v.x + v.y) + (v.z + v.w);
      ss = fmaf(v.x, v.x, fmaf(v.y, v.y, fmaf(v.z, v.z, fmaf(v.w, v.w, ss))));
    }
#pragma unroll
    for (int off = 16; off >= 1; off >>= 1) {  // stays within 32-lane group
      s += __shfl_xor(s, off, 64);
      ss += __shfl_xor(ss, off, 64);
    }
    if (cl == 0) {
      const float m = s * (1.0f / NL);
      sm[rw] = m;
      sr[rw] = rsqrtf(ss * (1.0f / NL) - m * m + 1e-5f);
    }
  }
  __syncthreads();

  // ---- Phase 3: style GEMM, register-double-buffered e ----
  float4 acc[2 * CB];
#pragma unroll
  for (int r = 0; r < 2 * CB; ++r) acc[r] = make_float4(0.f, 0.f, 0.f, 0.f);

#pragma unroll 1
  for (int q0 = 0; q0 < NQ; q0 += 4) {
    const float4 e0 = n0, e1 = n1, e2 = n2, e3 = n3;
    if (q0 + 4 < NQ) {
      const float4* nf = ef + (q0 + 4) * 256;
      n0 = nf[0 * 256];
      n1 = nf[1 * 256];
      n2 = nf[2 * 256];
      n3 = nf[3 * 256];
    }
#pragma unroll
    for (int r = 0; r < 2 * CB; ++r) {
      const float4 a = *reinterpret_cast<const float4*>(&As[r][q0]);
      fma4(acc[r], a.x, e0);
      fma4(acc[r], a.y, e1);
      fma4(acc[r], a.z, e2);
      fma4(acc[r], a.w, e3);
    }
  }

  // ---- Phase 4: apply ----
#pragma unroll
  for (int r = 0; r < CB; ++r) {
    const int c = c0 + r;
    const float vg = V[c], vb = V[c + NC];
    const float bg = bias[c], bb = bias[c + NC];
    const float m = sm[r], rs = sr[r];
    const float4 xv = *reinterpret_cast<const float4*>(&xs[r][t * 4]);
    const float4 g = acc[r];
    const float4 p = acc[r + CB];
    float4 o;
    o.x = fmaf(1.0f + g.x + fmaf(tv.x, vg, bg), (xv.x - m) * rs,
               p.x + fmaf(tv.x, vb, bb));
    o.y = fmaf(1.0f + g.y + fmaf(tv.y, vg, bg), (xv.y - m) * rs,
               p.y + fmaf(tv.y, vb, bb));
    o.z = fmaf(1.0f + g.z + fmaf(tv.z, vg, bg), (xv.z - m) * rs,
               p.z + fmaf(tv.z, vb, bb));
    o.w = fmaf(1.0f + g.w + fmaf(tv.w, vg, bg), (xv.w - m) * rs,
               p.w + fmaf(tv.w, vb, bb));
    reinterpret_cast<float4*>(out + (b * NC + c) * NL)[t] = o;
  }
}

// ---------------------------------------------------------------------------
extern "C" void kernel_launch(void* const* d_in, const int* in_sizes, int n_in,
                              void* d_out, int out_size, void* d_ws,
                              size_t ws_size, hipStream_t stream) {
  const float* x = (const float*)d_in[0];     // (16,256,1024)
  const float* u_i = (const float*)d_in[1];   // (16,64)
  const float* e = (const float*)d_in[2];     // (16,64,1024)
  const float* tt = (const float*)d_in[3];    // (16,1,1024)
  const float* W = (const float*)d_in[4];     // (512,4096)
  const float* V = (const float*)d_in[5];     // (512,1)
  const float* bias = (const float*)d_in[6];  // (512,)
  float* out = (float*)d_out;                 // (16,256,1024)

  float* A = (float*)d_ws;  // 16*512*64 floats = 2 MB

  calc_A_kernel<<<N2C, 256, 0, stream>>>(u_i, W, A);
  fused_kernel<<<NB * 32, 256, 0, stream>>>(x, e, tt, V, bias, A, out);
}